// Round 9
// baseline (39860.907 us; speedup 1.0000x reference)
//
#include <hip/hip_runtime.h>
#include <hip/hip_bf16.h>
#include <math.h>

#define CDIM 384
#define NW 49
#define NHEADS 12
#define HDIM 32
#define LROW 784
#define NROWS 50176        // B*L
#define MLPH 1536

typedef __hip_bfloat16 bf16;
__device__ __forceinline__ float b2f(bf16 v) { return __bfloat162float(v); }
__device__ __forceinline__ bf16 f2b(float v) { return __float2bfloat16(v); }

// ---------------- sentinel fill (fp32) ----------------
__global__ __launch_bounds__(256) void k_fill(float* out, int n, float val) {
  int i = blockIdx.x * 256 + threadIdx.x;
  if (i < n) out[i] = val;
}

// ---------------- LayerNorm, LDS-tree reduction, one block per row ----------------
// out bf16 variant (for xn1)
__global__ __launch_bounds__(256) void k_ln_b(const float* __restrict__ in,
                                              const float* __restrict__ g,
                                              const float* __restrict__ b,
                                              bf16* __restrict__ outp) {
  __shared__ float s1[256], s2[256];
  const int tid = threadIdx.x;
  const float* row = in + (size_t)blockIdx.x * CDIM;
  float a = row[tid];
  float c2 = (tid < CDIM - 256) ? row[tid + 256] : 0.f;
  s1[tid] = a + c2;
  s2[tid] = a * a + c2 * c2;
  __syncthreads();
  for (int s = 128; s > 0; s >>= 1) {
    if (tid < s) { s1[tid] += s1[tid + s]; s2[tid] += s2[tid + s]; }
    __syncthreads();
  }
  const float mean = s1[0] * (1.f / CDIM);
  const float var = s2[0] * (1.f / CDIM) - mean * mean;
  const float inv = rsqrtf(var + 1e-5f);
  bf16* orow = outp + (size_t)blockIdx.x * CDIM;
  orow[tid] = f2b((row[tid] - mean) * inv * g[tid] + b[tid]);
  if (tid < CDIM - 256)
    orow[tid + 256] = f2b((row[tid + 256] - mean) * inv * g[tid + 256] + b[tid + 256]);
}
// out fp32 variant (for xn2)
__global__ __launch_bounds__(256) void k_ln_f(const float* __restrict__ in,
                                              const float* __restrict__ g,
                                              const float* __restrict__ b,
                                              float* __restrict__ outp) {
  __shared__ float s1[256], s2[256];
  const int tid = threadIdx.x;
  const float* row = in + (size_t)blockIdx.x * CDIM;
  float a = row[tid];
  float c2 = (tid < CDIM - 256) ? row[tid + 256] : 0.f;
  s1[tid] = a + c2;
  s2[tid] = a * a + c2 * c2;
  __syncthreads();
  for (int s = 128; s > 0; s >>= 1) {
    if (tid < s) { s1[tid] += s1[tid + s]; s2[tid] += s2[tid + s]; }
    __syncthreads();
  }
  const float mean = s1[0] * (1.f / CDIM);
  const float var = s2[0] * (1.f / CDIM) - mean * mean;
  const float inv = rsqrtf(var + 1e-5f);
  float* orow = outp + (size_t)blockIdx.x * CDIM;
  orow[tid] = (row[tid] - mean) * inv * g[tid] + b[tid];
  if (tid < CDIM - 256)
    orow[tid + 256] = (row[tid + 256] - mean) * inv * g[tid + 256] + b[tid + 256];
}

// ---------------- QKV: one thread per (row, o) ----------------
__global__ __launch_bounds__(256) void k_qkv(const bf16* __restrict__ xn1,
                                             const float* __restrict__ qkv_w,
                                             const float* __restrict__ qkv_b,
                                             bf16* __restrict__ q, bf16* __restrict__ k,
                                             bf16* __restrict__ v) {
  size_t t = (size_t)blockIdx.x * 256 + threadIdx.x;
  if (t >= (size_t)NROWS * 1152) return;
  int o = (int)(t % 1152);
  int rg = (int)(t / 1152);
  const bf16* xr = xn1 + (size_t)rg * CDIM;
  const float* wr = qkv_w + (size_t)o * CDIM;
  float acc = 0.f;
  for (int kk = 0; kk < CDIM; ++kk) acc += b2f(xr[kk]) * wr[kk];
  acc += qkv_b[o];
  // destination: (win, head, n, d)
  int b = rg / LROW, l = rg - b * LROW;
  int hs = l / 28, ws = l - hs * 28;
  int wi = hs / 7, r7 = hs - wi * 7, wj = ws / 7, s7 = ws - wj * 7;
  int win = b * 16 + wi * 4 + wj;
  int n = r7 * 7 + s7;
  int h = o / 96, rem = o - h * 96, ty = rem / HDIM, d = rem % HDIM;
  bf16* dst = (ty == 0) ? q : ((ty == 1) ? k : v);
  dst[(((size_t)win * NHEADS + h) * NW + n) * HDIM + d] = f2b(acc);
}

// ---------------- attention: one thread per (win, h, n), full row serial ----------------
__global__ __launch_bounds__(256) void k_attn(const bf16* __restrict__ q,
                                              const bf16* __restrict__ k,
                                              const bf16* __restrict__ v,
                                              const float* __restrict__ attn_bias,
                                              const int* __restrict__ bias_idxs,
                                              int noff, bf16* __restrict__ outp) {
  size_t t = (size_t)blockIdx.x * 256 + threadIdx.x;
  if (t >= (size_t)1024 * NHEADS * NW) return;
  int n = (int)(t % NW);
  int h = (int)((t / NW) % NHEADS);
  int win = (int)(t / (NW * NHEADS));
  const size_t base = (((size_t)win * NHEADS + h) * NW) * HDIM;
  float qr[HDIM];
  for (int d = 0; d < HDIM; ++d) qr[d] = b2f(q[base + (size_t)n * HDIM + d]);
  float sc[NW];
  float mx = -1e30f;
  const float scale = 0.17677669529663687f;
  for (int m = 0; m < NW; ++m) {
    const bf16* kr = k + base + (size_t)m * HDIM;
    float s = 0.f;
    for (int d = 0; d < HDIM; ++d) s += qr[d] * b2f(kr[d]);
    s = s * scale + attn_bias[h * noff + bias_idxs[n * NW + m]];
    sc[m] = s;
    mx = fmaxf(mx, s);
  }
  float sum = 0.f;
  for (int m = 0; m < NW; ++m) {
    sc[m] = __expf(sc[m] - mx);
    sum += sc[m];
  }
  float inv = 1.f / sum;
  bf16* orow = outp + ((size_t)win * NW + n) * CDIM + h * HDIM;
  for (int d = 0; d < HDIM; ++d) {
    float acc = 0.f;
    for (int m = 0; m < NW; ++m) acc += sc[m] * b2f(v[base + (size_t)m * HDIM + d]);
    orow[d] = f2b(acc * inv);
  }
}

// ---------------- proj + residual: one thread per (wrow, c) ----------------
__global__ __launch_bounds__(256) void k_proj(const bf16* __restrict__ attn,
                                              const float* __restrict__ proj_w,
                                              const float* __restrict__ proj_b,
                                              const float* __restrict__ x_in,
                                              float* __restrict__ x1) {
  size_t t = (size_t)blockIdx.x * 256 + threadIdx.x;
  if (t >= (size_t)NROWS * CDIM) return;
  int c = (int)(t % CDIM);
  int wrow = (int)(t / CDIM);
  const bf16* ar = attn + (size_t)wrow * CDIM;
  const float* wr = proj_w + (size_t)c * CDIM;
  float acc = 0.f;
  for (int d = 0; d < CDIM; ++d) acc += b2f(ar[d]) * wr[d];
  int win = wrow / NW, n = wrow - win * NW;
  int b = win / 16, wrem = win % 16, wi = wrem / 4, wj = wrem % 4;
  int r7 = n / 7, s7 = n - r7 * 7;
  int l = (wi * 7 + r7) * 28 + (wj * 7 + s7);
  size_t dst = ((size_t)b * LROW + l) * CDIM + c;
  x1[dst] = x_in[dst] + acc + proj_b[c];
}

// ---------------- depthwise conv 3x3 + BN: one thread per (b,l,c) ----------------
__global__ __launch_bounds__(256) void k_conv(const float* __restrict__ x1,
                                              const float* __restrict__ cw,
                                              const float* __restrict__ bng,
                                              const float* __restrict__ bnb,
                                              const float* __restrict__ bnm,
                                              const float* __restrict__ bnv,
                                              float* __restrict__ x2) {
  size_t t = (size_t)blockIdx.x * 256 + threadIdx.x;
  if (t >= (size_t)NROWS * CDIM) return;
  int c = (int)(t % CDIM);
  int l = (int)((t / CDIM) % LROW);
  int b = (int)(t / ((size_t)CDIM * LROW));
  int h = l / 28, w = l - h * 28;
  float acc = 0.f;
  for (int dh = -1; dh <= 1; ++dh) {
    int hh = h + dh;
    if (hh < 0 || hh >= 28) continue;
    for (int dw = -1; dw <= 1; ++dw) {
      int ww = w + dw;
      if (ww < 0 || ww >= 28) continue;
      acc += x1[((size_t)b * LROW + hh * 28 + ww) * CDIM + c] * cw[c * 9 + (dh + 1) * 3 + (dw + 1)];
    }
  }
  float invs = rsqrtf(bnv[c] + 1e-5f);
  x2[t] = (acc - bnm[c]) * invs * bng[c] + bnb[c];
}

// ---------------- MLP: one block per row; FC1+GELU in LDS, FC2+residual (fp32 out) ----------------
__global__ __launch_bounds__(256) void k_mlp(const float* __restrict__ xn2,
                                             const float* __restrict__ fc1_w,
                                             const float* __restrict__ fc1_b,
                                             const float* __restrict__ fc2_w,
                                             const float* __restrict__ fc2_b,
                                             const float* __restrict__ x2,
                                             float* __restrict__ outp) {
  __shared__ float xrow[CDIM];
  __shared__ float hs[MLPH];
  const int tid = threadIdx.x;
  const size_t row = blockIdx.x;
  const float* xr = xn2 + row * CDIM;
  xrow[tid] = xr[tid];
  if (tid < CDIM - 256) xrow[tid + 256] = xr[tid + 256];
  __syncthreads();
  for (int oi = 0; oi < MLPH / 256; ++oi) {
    int o = tid + oi * 256;
    const float* wr = fc1_w + (size_t)o * CDIM;
    float acc = 0.f;
    for (int kk = 0; kk < CDIM; ++kk) acc += xrow[kk] * wr[kk];
    acc += fc1_b[o];
    hs[o] = 0.5f * acc * (1.f + erff(acc * 0.70710678118654752f));
  }
  __syncthreads();
  for (int ci = 0; ci < 2; ++ci) {
    int c = tid + ci * 256;
    if (c >= CDIM) break;
    const float* wr = fc2_w + (size_t)c * MLPH;
    float acc = 0.f;
    for (int m = 0; m < MLPH; ++m) acc += hs[m] * wr[m];
    outp[row * CDIM + c] = x2[row * CDIM + c] + acc + fc2_b[c];
  }
}

extern "C" void kernel_launch(void* const* d_in, const int* in_sizes, int n_in,
                              void* d_out, int out_size, void* d_ws, size_t ws_size,
                              hipStream_t stream) {
  float* out = (float*)d_out;  // reference output dtype is float32
  // ---- host-side input-order validation + size-class remap (identity-verified in R8) ----
  static const int EXP[20] = {19267584, 384, 384, 442368, 1152, 588, 2401, 147456, 384, 3456,
                              384, 384, 384, 384, 384, 384, 589824, 1536, 589824, 384};
  const void* p[20];
  bool ok = (n_in == 20);
  int badslot = 30;
  if (ok) {
    bool used[20] = {false};
    for (int i = 0; i < 20 && ok; ++i) {
      int occ = 0;
      for (int j = 0; j < i; ++j) if (EXP[j] == EXP[i]) ++occ;
      int found = -1, seen = 0;
      for (int j = 0; j < 20; ++j) {
        if (in_sizes[j] == EXP[i]) {
          if (seen == occ) { found = j; break; }
          ++seen;
        }
      }
      if (found < 0 || used[found]) { ok = false; badslot = i; break; }
      used[found] = true;
      p[i] = d_in[found];
    }
  }
  const int NOUT = NROWS * CDIM;
  if (!ok) {
    k_fill<<<(NOUT + 255) / 256, 256, 0, stream>>>(out, NOUT, -(2.0f + 0.05f * badslot));
    return;
  }
  // ---- workspace layout, peak 154.2 MB (known-safe: 161 MB used in R3) ----
  const size_t RB = (size_t)NROWS * CDIM;  // 19,267,584
  if (ws_size < RB * 8 + 1024) {
    k_fill<<<(NOUT + 255) / 256, 256, 0, stream>>>(out, NOUT, -5.0f);
    return;
  }
  char* base = (char*)d_ws;
  bf16* xn1 = (bf16*)base;                 // [0, 38.5 MB)
  bf16* q = (bf16*)(base + RB * 2);        // [38.5, 77.1)
  bf16* k = (bf16*)(base + RB * 4);        // [77.1, 115.6)
  bf16* v = (bf16*)(base + RB * 6);        // [115.6, 154.2)
  bf16* attn = (bf16*)d_out;               // bf16 scratch in d_out front half; fully overwritten by k_mlp fp32 writes
  float* x1 = (float*)base;                // reuse [0, 77.1): xn1,q dead after attn
  float* x2 = (float*)(base + RB * 4);     // reuse [77.1, 154.2): k,v dead after attn
  float* xn2 = (float*)base;               // reuse [0, 77.1): x1 dead after conv

  const float* xin = (const float*)p[0];
  const int noff = 49;

  k_ln_b<<<NROWS, 256, 0, stream>>>(xin, (const float*)p[1], (const float*)p[2], xn1);
  k_qkv<<<(int)(((size_t)NROWS * 1152 + 255) / 256), 256, 0, stream>>>(
      xn1, (const float*)p[3], (const float*)p[4], q, k, v);
  k_attn<<<(int)(((size_t)1024 * NHEADS * NW + 255) / 256), 256, 0, stream>>>(
      q, k, v, (const float*)p[5], (const int*)p[6], noff, attn);
  k_proj<<<(NOUT + 255) / 256, 256, 0, stream>>>(
      attn, (const float*)p[7], (const float*)p[8], xin, x1);
  k_conv<<<(NOUT + 255) / 256, 256, 0, stream>>>(
      x1, (const float*)p[9], (const float*)p[10], (const float*)p[11],
      (const float*)p[12], (const float*)p[13], x2);
  k_ln_f<<<NROWS, 256, 0, stream>>>(x2, (const float*)p[14], (const float*)p[15], xn2);
  k_mlp<<<NROWS, 256, 0, stream>>>(
      xn2, (const float*)p[16], (const float*)p[17], (const float*)p[18],
      (const float*)p[19], x2, out);
}